// Round 5
// baseline (350.118 us; speedup 1.0000x reference)
//
#include <hip/hip_runtime.h>
#include <hip/hip_bf16.h>

typedef __bf16 bf16_t;
typedef __bf16 bf16x2 __attribute__((ext_vector_type(2)));
typedef __bf16 bf16x4 __attribute__((ext_vector_type(4)));
typedef __bf16 bf16x8 __attribute__((ext_vector_type(8)));
typedef float f32x2 __attribute__((ext_vector_type(2)));
typedef float f32x4 __attribute__((ext_vector_type(4)));
typedef unsigned int u32;

#define MFMA16(a, b, c) __builtin_amdgcn_mfma_f32_16x16x32_bf16(a, b, c, 0, 0, 0)

__device__ inline float ldf(const void* p, int i, int f32) {
    return f32 ? ((const float*)p)[i] : (float)((const bf16_t*)p)[i];
}

// ---------------------------------------------------------------------------
// probe_dtype: one wave decides fp32 vs bf16, writes flags[0].
// ---------------------------------------------------------------------------
__global__ void probe_dtype(const u32* __restrict__ x, int* __restrict__ flags) {
    u32 v = x[threadIdx.x];
    int f = (((v >> 7) & 0xFFu) >= 0x90u) || (((v >> 23) & 0xFFu) >= 0x90u);
    f = __any(f);
    if (threadIdx.x == 0) flags[0] = f ? 1 : 0;
}

// ---------------------------------------------------------------------------
// conv_norm: xn[token] = LayerNorm_noaffine(x[token]) as bf16. One wave/token.
// ---------------------------------------------------------------------------
__global__ __launch_bounds__(256) void conv_norm(const void* __restrict__ xv,
                                                 const int* __restrict__ flags,
                                                 u32* __restrict__ xn) {
    const int f32 = flags[0];
    int t = blockIdx.x * 4 + (threadIdx.x >> 6);
    int lane = threadIdx.x & 63;
    float f0, f1;
    if (f32) {
        f32x2 v = *(const f32x2*)((const float*)xv + t * 128 + lane * 2);
        f0 = v[0]; f1 = v[1];
    } else {
        u32 w = ((const u32*)xv)[t * 64 + lane];
        f0 = __builtin_bit_cast(float, w << 16);
        f1 = __builtin_bit_cast(float, w & 0xFFFF0000u);
    }
    float s = f0 + f1, s2 = f0 * f0 + f1 * f1;
#pragma unroll
    for (int off = 32; off >= 1; off >>= 1) {
        s += __shfl_xor(s, off, 64);
        s2 += __shfl_xor(s2, off, 64);
    }
    float mu = s * (1.f / 128.f);
    float r = rsqrtf(s2 * (1.f / 128.f) - mu * mu + 1e-5f);
    bf16x2 h = { (bf16_t)((f0 - mu) * r), (bf16_t)((f1 - mu) * r) };
    xn[t * 64 + lane] = __builtin_bit_cast(u32, h);
}

// ---------------------------------------------------------------------------
// prep_fold: W'[j][c] = qkv_w[j][c]*g[c] (bf16); u[j]=sum g*W; t[j]=sum b*W+qb
// ---------------------------------------------------------------------------
__global__ void prep_fold(const int* __restrict__ flags, const void* __restrict__ qw,
                          const void* __restrict__ qb, const void* __restrict__ ng,
                          const void* __restrict__ nb, bf16_t* __restrict__ Wp,
                          float* __restrict__ uu, float* __restrict__ tt) {
    const int f32 = flags[0];
    int j = blockIdx.x;
    int l = threadIdx.x;
    float g0 = ldf(ng, l, f32),  g1 = ldf(ng, l + 64, f32);
    float b0 = ldf(nb, l, f32),  b1 = ldf(nb, l + 64, f32);
    float w0 = ldf(qw, j * 128 + l, f32), w1 = ldf(qw, j * 128 + l + 64, f32);
    float wg0 = w0 * g0, wg1 = w1 * g1;
    Wp[j * 128 + l] = (bf16_t)wg0;
    Wp[j * 128 + l + 64] = (bf16_t)wg1;
    float su = wg0 + wg1;
    float st = w0 * b0 + w1 * b1;
#pragma unroll
    for (int off = 32; off >= 1; off >>= 1) {
        su += __shfl_xor(su, off, 64);
        st += __shfl_xor(st, off, 64);
    }
    if (l == 0) { uu[j] = su; tt[j] = st + ldf(qb, j, f32); }
}

// ---------------------------------------------------------------------------
// prep_pos: DPB MLP, 961 rows, ONE block; all 252 weights staged in LDS once.
// W offsets: ppw 0, ppb 16, l1g 24, l1b 32, f1w 40, f1b 104, l2g 112,
//            l2b 120, f2w 128, f2b 192, l3g 200, l3b 208, f3w 216, f3b 248
// ---------------------------------------------------------------------------
__device__ inline void ln8s(float* p, const float* g, const float* b) {
    float m = 0.f;
#pragma unroll
    for (int i = 0; i < 8; ++i) m += p[i];
    m *= 0.125f;
    float v = 0.f;
#pragma unroll
    for (int i = 0; i < 8; ++i) { float d = p[i] - m; v += d * d; }
    v *= 0.125f;
    float r = rsqrtf(v + 1e-5f);
#pragma unroll
    for (int i = 0; i < 8; ++i)
        p[i] = fmaxf((p[i] - m) * r * g[i] + b[i], 0.f);
}

__global__ __launch_bounds__(1024) void prep_pos(
    const int* __restrict__ flags,
    const void* __restrict__ ppw, const void* __restrict__ ppb,
    const void* __restrict__ l1g, const void* __restrict__ l1b,
    const void* __restrict__ f1w, const void* __restrict__ f1b,
    const void* __restrict__ l2g, const void* __restrict__ l2b,
    const void* __restrict__ f2w, const void* __restrict__ f2b,
    const void* __restrict__ l3g, const void* __restrict__ l3b,
    const void* __restrict__ f3w, const void* __restrict__ f3b,
    float* __restrict__ pos) {
    const int f32 = flags[0];
    __shared__ float W[256];
    int t = threadIdx.x;
    if (t < 252) {
        const void* src; int off;
        if (t < 16)       { src = ppw; off = t; }
        else if (t < 24)  { src = ppb; off = t - 16; }
        else if (t < 32)  { src = l1g; off = t - 24; }
        else if (t < 40)  { src = l1b; off = t - 32; }
        else if (t < 104) { src = f1w; off = t - 40; }
        else if (t < 112) { src = f1b; off = t - 104; }
        else if (t < 120) { src = l2g; off = t - 112; }
        else if (t < 128) { src = l2b; off = t - 120; }
        else if (t < 192) { src = f2w; off = t - 128; }
        else if (t < 200) { src = f2b; off = t - 192; }
        else if (t < 208) { src = l3g; off = t - 200; }
        else if (t < 216) { src = l3b; off = t - 208; }
        else if (t < 248) { src = f3w; off = t - 216; }
        else              { src = f3b; off = t - 248; }
        W[t] = ldf(src, off, f32);
    }
    __syncthreads();
    if (t >= 961) return;
    float bh = (float)(t / 31) - 15.f;
    float bw = (float)(t % 31) - 15.f;
    float p[8], q[8];
#pragma unroll
    for (int i = 0; i < 8; ++i)
        p[i] = W[i * 2] * bh + W[i * 2 + 1] * bw + W[16 + i];
    ln8s(p, W + 24, W + 32);
#pragma unroll
    for (int o = 0; o < 8; ++o) {
        float s = W[104 + o];
#pragma unroll
        for (int i = 0; i < 8; ++i) s += p[i] * W[40 + o * 8 + i];
        q[o] = s;
    }
    ln8s(q, W + 112, W + 120);
#pragma unroll
    for (int o = 0; o < 8; ++o) {
        float s = W[192 + o];
#pragma unroll
        for (int i = 0; i < 8; ++i) s += q[i] * W[128 + o * 8 + i];
        p[o] = s;
    }
    ln8s(p, W + 200, W + 208);
#pragma unroll
    for (int o = 0; o < 4; ++o) {
        float s = W[248 + o];
#pragma unroll
        for (int i = 0; i < 8; ++i) s += p[i] * W[216 + o * 8 + i];
        pos[t * 4 + o] = s;
    }
}

// ---------------------------------------------------------------------------
// win_attn: one block per (window, head); 4 waves; wave owns 64 q-tokens.
// S^T = K Q^T orientation; P^T via ds_bpermute; K/V software-prefetched;
// head bits placed so 4 sibling heads share an XCD (L2 reuse on xn);
// epilogue transposes O through LDS for full-line global writes.
// ---------------------------------------------------------------------------
template <int XN>
__global__ __launch_bounds__(256, 4) void win_attn(
    const void* __restrict__ xv, const bf16_t* __restrict__ xnp,
    const bf16_t* __restrict__ Wp, const float* __restrict__ uu,
    const float* __restrict__ tt, const float* __restrict__ posg,
    const int* __restrict__ flags, void* __restrict__ outv) {
    constexpr int SMEM_SZ = XN ? 39684 : 42116;
    __shared__ __align__(16) char smem[SMEM_SZ];
    bf16_t* k_s   = (bf16_t*)smem;            // 256*40*2 = 20480
    bf16_t* vT_s  = (bf16_t*)(smem + 20480);  // 32*264*2 = 16896 -> 37376
    bf16_t* pos_s = (bf16_t*)(smem + 37376);  // 962*2    = 1924  -> 39300
    float*  tt_s  = (float*)(smem + 39300);   // 96*4     = 384   -> 39684
    float*  uu_s  = (float*)(smem + 39684);   // XN=0 only
    float*  mu_s  = (float*)(smem + 40068);
    float*  r_s   = (float*)(smem + 41092);

    const int f32 = flags[0];
    const int tid = threadIdx.x;
    const int lane = tid & 63;
    const int w = tid >> 6;
    const int l15 = lane & 15;
    const int quad = lane >> 4;
    // sibling heads differ only in bits 3..4 => same (blockIdx % 8) => same XCD
    const int head = (blockIdx.x >> 3) & 3;
    const int wi = (blockIdx.x & 7) | ((blockIdx.x >> 5) << 3);
    const int bi = wi >> 8;
    const int wh = (wi >> 4) & 15, ww = wi & 15;
    const int xbase = bi * (256 * 256 * 128);

    if (tid < 96) {
        int sg = tid >> 5, dd = tid & 31;
        tt_s[tid] = tt[sg * 128 + head * 32 + dd];
        if (!XN) uu_s[tid] = uu[sg * 128 + head * 32 + dd];
    }
    for (int r = tid; r < 961; r += 256) pos_s[r] = (bf16_t)posg[r * 4 + head];

    if (!XN) {
#pragma unroll
        for (int it = 0; it < 4; ++it) {
            int i = w * 64 + it * 16 + (lane >> 2);
            int gi = xbase + ((wh * 16 + (i >> 4)) * 256 + ww * 16 + (i & 15)) * 128;
            float s = 0.f, s2 = 0.f;
            if (f32) {
                const f32x4* p4 = (const f32x4*)((const float*)xv + gi);
#pragma unroll
                for (int c = 0; c < 4; ++c) {
                    f32x4 a = p4[(c * 4 + (lane & 3)) * 2];
                    f32x4 b = p4[(c * 4 + (lane & 3)) * 2 + 1];
#pragma unroll
                    for (int e = 0; e < 4; ++e) { s += a[e] + b[e]; s2 += a[e] * a[e] + b[e] * b[e]; }
                }
            } else {
                const bf16_t* p = (const bf16_t*)xv + gi;
#pragma unroll
                for (int c = 0; c < 4; ++c) {
                    bf16x8 v = *(const bf16x8*)(p + (c * 4 + (lane & 3)) * 8);
#pragma unroll
                    for (int e = 0; e < 8; ++e) { float f = (float)v[e]; s += f; s2 += f * f; }
                }
            }
            s  += __shfl_xor(s, 1, 4);  s  += __shfl_xor(s, 2, 4);
            s2 += __shfl_xor(s2, 1, 4); s2 += __shfl_xor(s2, 2, 4);
            if ((lane & 3) == 0) {
                float mu = s * (1.f / 128.f);
                mu_s[i] = mu;
                r_s[i] = rsqrtf(s2 * (1.f / 128.f) - mu * mu + 1e-5f);
            }
        }
    }
    __syncthreads();  // tt_s / pos_s (/stats) ready

    // ---- QKV GEMM, sel-outer ----
    int axi[4];
#pragma unroll
    for (int mt = 0; mt < 4; ++mt) {
        int i = w * 64 + mt * 16 + l15;
        axi[mt] = xbase + ((wh * 16 + (i >> 4)) * 256 + ww * 16 + (i & 15)) * 128;
    }
    const float qscale = 0.17677669529663689f;  // 1/sqrt(32)
    bf16x8 qB[4];

#pragma unroll 1
    for (int sel = 0; sel < 3; ++sel) {
        f32x4 acc[2][4];
#pragma unroll
        for (int nt = 0; nt < 2; ++nt)
#pragma unroll
            for (int mt = 0; mt < 4; ++mt) acc[nt][mt] = f32x4{0.f, 0.f, 0.f, 0.f};
        const bf16_t* bw0 = Wp + (sel * 128 + head * 32 + l15) * 128;
        const bf16_t* bw1 = bw0 + 16 * 128;
#pragma unroll
        for (int ks = 0; ks < 4; ++ks) {
            int ko = ks * 32 + quad * 8;
            bf16x8 af[4];
            if (XN) {
#pragma unroll
                for (int mt = 0; mt < 4; ++mt)
                    af[mt] = *(const bf16x8*)(xnp + axi[mt] + ko);
            } else if (f32) {
#pragma unroll
                for (int mt = 0; mt < 4; ++mt) {
                    const float* pp = (const float*)xv + axi[mt] + ko;
                    f32x4 u0 = *(const f32x4*)pp;
                    f32x4 u1 = *(const f32x4*)(pp + 4);
                    bf16x8 tb;
#pragma unroll
                    for (int e = 0; e < 4; ++e) { tb[e] = (bf16_t)u0[e]; tb[e + 4] = (bf16_t)u1[e]; }
                    af[mt] = tb;
                }
            } else {
#pragma unroll
                for (int mt = 0; mt < 4; ++mt)
                    af[mt] = *(const bf16x8*)((const bf16_t*)xv + axi[mt] + ko);
            }
            bf16x8 b0 = *(const bf16x8*)(bw0 + ko);
            bf16x8 b1 = *(const bf16x8*)(bw1 + ko);
#pragma unroll
            for (int mt = 0; mt < 4; ++mt) {
                acc[0][mt] = MFMA16(af[mt], b0, acc[0][mt]);
                acc[1][mt] = MFMA16(af[mt], b1, acc[1][mt]);
            }
        }
#pragma unroll
        for (int nt = 0; nt < 2; ++nt) {
            int d = nt * 16 + l15;
            float tj = tt_s[sel * 32 + d];
            float uj = XN ? 0.f : uu_s[sel * 32 + d];
#pragma unroll
            for (int mt = 0; mt < 4; ++mt)
#pragma unroll
                for (int rg = 0; rg < 4; ++rg) {
                    int token = w * 64 + mt * 16 + quad * 4 + rg;
                    float val;
                    if (XN) val = acc[nt][mt][rg] + tj;
                    else    val = r_s[token] * (acc[nt][mt][rg] - mu_s[token] * uj) + tj;
                    if (sel == 0)      k_s[token * 40 + d] = (bf16_t)(val * qscale);
                    else if (sel == 1) k_s[token * 40 + d] = (bf16_t)val;
                    else               vT_s[d * 264 + token] = (bf16_t)val;
                }
        }
        if (sel == 0) {
#pragma unroll
            for (int qt = 0; qt < 4; ++qt)
                qB[qt] = *(const bf16x8*)(k_s + (w * 64 + qt * 16 + l15) * 40 + quad * 8);
            __syncthreads();  // WAR: q reads done before K overwrites
        }
    }
    __syncthreads();  // K / V^T visible

    // ---- kb loop: S^T = K Q^T, bpermute P^T, O^T = V^T P^T ----
    f32x4 Oa[2][4];
#pragma unroll
    for (int np = 0; np < 2; ++np)
#pragma unroll
        for (int qt = 0; qt < 4; ++qt) Oa[np][qt] = f32x4{0.f, 0.f, 0.f, 0.f};
    float lsum[4] = {0.f, 0.f, 0.f, 0.f};

    const f32x4 zero4 = {0.f, 0.f, 0.f, 0.f};
    const int idxA = ((2 * (quad & 1)) * 16 + l15) * 4;
    const int idxB = idxA + 64;
    const bool hi_nt = (lane & 32) != 0;
    const int vinner = l15 + 15 - quad * 4;

    bf16x8 kpre[2], vpre[2];
#pragma unroll
    for (int nt = 0; nt < 2; ++nt) {
        kpre[nt] = *(const bf16x8*)(k_s + (nt * 16 + l15) * 40 + quad * 8);
        vpre[nt] = *(const bf16x8*)(vT_s + (nt * 16 + l15) * 264 + quad * 8);
    }

#pragma unroll
    for (int kb = 0; kb < 8; ++kb) {
        bf16x8 kc[2] = { kpre[0], kpre[1] };
        bf16x8 vc[2] = { vpre[0], vpre[1] };
        if (kb < 7) {
#pragma unroll
            for (int nt = 0; nt < 2; ++nt) {
                kpre[nt] = *(const bf16x8*)(k_s + ((kb + 1) * 32 + nt * 16 + l15) * 40 + quad * 8);
                vpre[nt] = *(const bf16x8*)(vT_s + (nt * 16 + l15) * 264 + (kb + 1) * 32 + quad * 8);
            }
        }
        u32 Pd[2][4][2];
#pragma unroll
        for (int nt = 0; nt < 2; ++nt) {
            f32x4 S[4];
#pragma unroll
            for (int qt = 0; qt < 4; ++qt) S[qt] = MFMA16(kc[nt], qB[qt], zero4);
#pragma unroll
            for (int qt = 0; qt < 4; ++qt) {
                int souter = (w * 4 + qt - kb * 2 - nt + 15) * 31;
                float p[4];
#pragma unroll
                for (int rg = 0; rg < 4; ++rg) {
                    float b = (float)pos_s[souter + vinner - rg];
                    p[rg] = __expf(S[qt][rg] + b);
                }
                lsum[qt] += (p[0] + p[1]) + (p[2] + p[3]);
                bf16x2 h0 = { (bf16_t)p[0], (bf16_t)p[1] };
                bf16x2 h1 = { (bf16_t)p[2], (bf16_t)p[3] };
                Pd[nt][qt][0] = __builtin_bit_cast(u32, h0);
                Pd[nt][qt][1] = __builtin_bit_cast(u32, h1);
            }
        }
        bf16x8 pB[4];
#pragma unroll
        for (int qt = 0; qt < 4; ++qt) {
            u32 dw[4];
#pragma unroll
            for (int half = 0; half < 2; ++half) {
                u32 a0 = (u32)__builtin_amdgcn_ds_bpermute(idxA, (int)Pd[0][qt][half]);
                u32 a1 = (u32)__builtin_amdgcn_ds_bpermute(idxA, (int)Pd[1][qt][half]);
                dw[half] = hi_nt ? a1 : a0;
                u32 b0 = (u32)__builtin_amdgcn_ds_bpermute(idxB, (int)Pd[0][qt][half]);
                u32 b1 = (u32)__builtin_amdgcn_ds_bpermute(idxB, (int)Pd[1][qt][half]);
                dw[2 + half] = hi_nt ? b1 : b0;
            }
            pB[qt] = __builtin_bit_cast(bf16x8, dw);
        }
#pragma unroll
        for (int np = 0; np < 2; ++np)
#pragma unroll
            for (int qt = 0; qt < 4; ++qt)
                Oa[np][qt] = MFMA16(vc[np], pB[qt], Oa[np][qt]);
    }

    // ---- epilogue: reduce lsum; transpose O via LDS; full-line stores ----
    float inv[4];
#pragma unroll
    for (int qt = 0; qt < 4; ++qt) {
        float l = lsum[qt];
        l += __shfl_xor(l, 16, 64);
        l += __shfl_xor(l, 32, 64);
        inv[qt] = 1.f / l;
    }
    __syncthreads();  // everyone done with k_s/vT_s; reuse as f32 scratch
    float* scr = (float*)smem + w * 2304;  // 64 tokens x stride 36
#pragma unroll
    for (int np = 0; np < 2; ++np)
#pragma unroll
        for (int qt = 0; qt < 4; ++qt) {
            f32x4 v;
#pragma unroll
            for (int rg = 0; rg < 4; ++rg) v[rg] = Oa[np][qt][rg] * inv[qt];
            *(f32x4*)(scr + (qt * 16 + l15) * 36 + np * 16 + quad * 4) = v;
        }
    // wave-private scratch: no barrier needed before readback
#pragma unroll
    for (int i = 0; i < 8; ++i) {
        int tok = i * 8 + (lane >> 3);
        f32x4 v = *(const f32x4*)(scr + tok * 36 + (lane & 7) * 4);
        int row = wh * 16 + w * 4 + (i >> 1);
        int col = ww * 16 + (i & 1) * 8 + (lane >> 3);
        int go = xbase + (row * 256 + col) * 128 + head * 32 + (lane & 7) * 4;
        if (f32) {
            f32x4 res = *(const f32x4*)((const float*)xv + go);
#pragma unroll
            for (int e = 0; e < 4; ++e) v[e] += res[e];
            *(f32x4*)((float*)outv + go) = v;
        } else {
            bf16x4 res = *(const bf16x4*)((const bf16_t*)xv + go);
            bf16x4 o;
#pragma unroll
            for (int e = 0; e < 4; ++e) o[e] = (bf16_t)(v[e] + (float)res[e]);
            *(bf16x4*)((bf16_t*)outv + go) = o;
        }
    }
}

extern "C" void kernel_launch(void* const* d_in, const int* in_sizes, int n_in,
                              void* d_out, int out_size, void* d_ws, size_t ws_size,
                              hipStream_t stream) {
    const void* x   = d_in[0];
    const void* ng  = d_in[1];
    const void* nb  = d_in[2];
    const void* qw  = d_in[3];
    const void* qb  = d_in[4];
    const void* ppw = d_in[5];
    const void* ppb = d_in[6];
    const void* l1g = d_in[7];
    const void* l1b = d_in[8];
    const void* f1w = d_in[9];
    const void* f1b = d_in[10];
    const void* l2g = d_in[11];
    const void* l2b = d_in[12];
    const void* f2w = d_in[13];
    const void* f2b = d_in[14];
    const void* l3g = d_in[15];
    const void* l3b = d_in[16];
    const void* f3w = d_in[17];
    const void* f3b = d_in[18];

    char* ws = (char*)d_ws;
    int*    flags = (int*)ws;                 // @0, 16 B
    bf16_t* Wp    = (bf16_t*)(ws + 16);       // 98304 B
    float*  uu    = (float*)(ws + 98320);     // 1536 B
    float*  tt    = (float*)(ws + 99856);     // 1536 B
    float*  pos   = (float*)(ws + 101392);    // 15376 B
    bf16_t* xn    = (bf16_t*)(ws + 116768);   // 33554432 B
    const int use_xn = (ws_size >= 116768 + 33554432u) ? 1 : 0;

    probe_dtype<<<dim3(1), dim3(64), 0, stream>>>((const u32*)x, flags);
    if (use_xn)
        conv_norm<<<dim3(32768), dim3(256), 0, stream>>>(x, flags, (u32*)xn);
    prep_fold<<<dim3(384), dim3(64), 0, stream>>>(flags, qw, qb, ng, nb, Wp, uu, tt);
    prep_pos<<<dim3(1), dim3(1024), 0, stream>>>(flags, ppw, ppb, l1g, l1b, f1w, f1b,
                                                 l2g, l2b, f2w, f2b, l3g, l3b,
                                                 f3w, f3b, pos);
    if (use_xn)
        win_attn<1><<<dim3(2048), dim3(256), 0, stream>>>(x, xn, Wp, uu, tt, pos,
                                                          flags, d_out);
    else
        win_attn<0><<<dim3(2048), dim3(256), 0, stream>>>(x, xn, Wp, uu, tt, pos,
                                                          flags, d_out);
}